// Round 6
// baseline (152.940 us; speedup 1.0000x reference)
//
#include <hip/hip_runtime.h>
#include <hip/hip_cooperative_groups.h>
#include <stdint.h>

namespace cg = cooperative_groups;

// ---------------------------------------------------------------------------
// Speaker pairwise loss. R15 = R14 (145.0us, proven: 8-wave blocks, 32x64
// per-wave tiles, 16 waves/CU, no spill) + three stall cuts, structure kept:
//  (1) ONE barrier per kc instead of two: stage(nxt) -> compute(cur) ->
//      vmcnt(0)+lgkmcnt(0) -> barrier. The single barrier proves both
//      "all stage writes landed" and "all reads of cur retired" (disjoint
//      dbuf halves). 8 -> 4 barriers per off-tile.
//  (2) Epilogue operands (labels/tmn/tmx) hoisted ABOVE the kc loop —
//      loop-invariant, so their ~300cyc L2 latency hides under the GEMM
//      instead of stalling the epilogue head.
//  (3) rp/cp stores nontemporal: stops write-allocate from evicting fb
//      (4MB, should stay L2-resident) — FETCH was 135MB vs ~45MB compulsory;
//      HBM refetch latency (~900cy) is what the 1-chunk prefetch can't hide.
// Math, K-order, swizzle, layouts identical to R14 -> absmax 0.0 expected.
// Occupancy is register-capped at 16 waves/CU (96 regs -> 128 granule);
// LDS 67KB caps at the same 16 -> balanced, axis exhausted.
// ws: fb bf16[B*D] | rp0/rp1[512*256] | cp0/cp1[64*33*512] | tmn[B] tmx[B]
// ---------------------------------------------------------------------------

typedef __attribute__((ext_vector_type(8))) short short8;   // 8 bf16
typedef __attribute__((ext_vector_type(4))) float floatx4;  // MFMA C/D

constexpr int D = 256;
constexpr int BM = 128;
constexpr int NT = 64;                    // 8192/128 strips
constexpr int GPS = 8;                    // groups per strip
constexpr int NPB = NT * GPS;             // 512 pair blocks
constexpr int CPS = 33;                   // cp slots per strip (off 0..32)
constexpr int BT = 512;                   // block threads (8 waves)
constexpr int CHUNK_SH = BM * 64;         // 8192 shorts = 16KB per buffer

__device__ __forceinline__ unsigned f2bf(float f) {  // fp32 -> bf16, RNE
  unsigned u = __float_as_uint(f);
  return (u + 0x7FFFu + ((u >> 16) & 1u)) >> 16;
}

__device__ __forceinline__ void gl_lds16(const void* g, void* l) {
  __builtin_amdgcn_global_load_lds(
      (const __attribute__((address_space(1))) unsigned int*)g,
      (__attribute__((address_space(3))) unsigned int*)l, 16, 0, 0);
}

// ---------------- pair body (8 waves, 32x64/wave, 1-barrier kc loop) --------
template <int PASS>
__device__ __forceinline__ void pair_body(
    int bid, const unsigned short* __restrict__ fb, const int* __restrict__ labels,
    const float* __restrict__ tmn, const float* __restrict__ tmx,
    float* __restrict__ rp0, float* __restrict__ rp1,
    float* __restrict__ cp0, float* __restrict__ cp1,
    short* As, short* Bs, int* labA, float* tA0, float* tA1) {
  const int I   = bid >> 3;
  const int g   = bid & 7;
  const int nT  = (I < 32) ? 33 : 32;
  const int t0  = (g * nT) >> 3;
  const int t1  = ((g + 1) * nT) >> 3;
  const int row0 = I * BM;

  const int tid  = threadIdx.x;
  const int lane = tid & 63;
  const int wave = tid >> 6;               // 0..7
  const int l15  = lane & 15;
  const int quad = lane >> 4;
  const int wr   = (wave >> 1) * 32;       // row offset: 0,32,64,96
  const int wc   = (wave & 1) * 64;        // col offset: 0,64

  const float ONE_EPS = 1.0f - 1e-5f;
  const float INF = __builtin_inff();

  __syncthreads();                       // protect smem vs previous phase
  if (tid < BM) {
    labA[tid] = labels[row0 + tid];
    if (PASS == 2) { tA0[tid] = tmn[row0 + tid]; tA1[tid] = tmx[row0 + tid]; }
  }

  // Stage one 64-col chunk of A-strip + column-strip into LDS buffer b.
  // Linear LDS dest (gl_lds constraint); XOR swizzle on GLOBAL source:
  // slot sl of row r holds global col-block sl^(r&7) (proven 0-conflict).
  auto stage = [&](int b, int col0, int kc) {
#pragma unroll
    for (int j = 0; j < 2; ++j) {
      int idx = j * BT + tid;            // 0..1023
      int r   = idx >> 3;                // row 0..127
      int sl  = idx & 7;                 // 16B slot within 128B row
      int cb  = sl ^ (r & 7);
      const char* ga = (const char*)fb + (((size_t)(row0 + r)) << 9) + (kc << 7) + (cb << 4);
      const char* gb = (const char*)fb + (((size_t)(col0 + r)) << 9) + (kc << 7) + (cb << 4);
      gl_lds16(ga, (char*)As + (size_t)b * (CHUNK_SH * 2) + ((size_t)idx << 4));
      gl_lds16(gb, (char*)Bs + (size_t)b * (CHUNK_SH * 2) + ((size_t)idx << 4));
    }
  };

  int arow[2], brow[4];
#pragma unroll
  for (int i = 0; i < 2; ++i) arow[i] = wr + i * 16 + l15;
#pragma unroll
  for (int i = 0; i < 4; ++i) brow[i] = wc + i * 16 + l15;

  float s0[8], s1[8];
#pragma unroll
  for (int i = 0; i < 8; ++i) {
    s0[i] = (PASS == 1) ? INF : 0.f;
    s1[i] = (PASS == 1) ? -INF : 0.f;
  }

  // prologue: stage first chunk, wait, barrier — invariant entering the loop:
  // buf[cur] is fully staged for everyone.
  stage(0, ((I + t0) & 63) * BM, 0);
  asm volatile("s_waitcnt vmcnt(0)" ::: "memory");
  __builtin_amdgcn_s_barrier();
  asm volatile("" ::: "memory");

  int cur = 0;
  for (int off = t0; off < t1; ++off) {
    const int J = (I + off) & 63;
    const int col0 = J * BM;
    const bool diag = (off == 0);

    // hoisted epilogue operands: loop-invariant over kc, issued before the
    // GEMM so their latency hides under it. (Loads can't sink below the
    // "memory"-clobber asm inside the kc loop.)
    int labc[4];
    float tBn[4], tBx[4];
#pragma unroll
    for (int cf = 0; cf < 4; ++cf) {
      int ci = col0 + wc + cf * 16 + l15;
      labc[cf] = labels[ci];
      if (PASS == 2) { tBn[cf] = tmn[ci]; tBx[cf] = tmx[ci]; }
    }

    floatx4 acc[2][4];
#pragma unroll
    for (int rf = 0; rf < 2; ++rf)
#pragma unroll
      for (int cf = 0; cf < 4; ++cf)
        acc[rf][cf] = (floatx4)(0.f);

#pragma unroll
    for (int kc = 0; kc < 4; ++kc) {
      // issue next chunk's stage into the alternate buffer FIRST — its
      // latency is covered by this chunk's compute phase.
      if (kc < 3)                stage(cur ^ 1, col0, kc + 1);
      else if (off + 1 < t1)     stage(cur ^ 1, ((I + off + 1) & 63) * BM, 0);

      const short* Ab = As + cur * CHUNK_SH;
      const short* Bb = Bs + cur * CHUNK_SH;
#pragma unroll
      for (int ks = 0; ks < 2; ++ks) {
        const int gg = ks * 4 + quad;
        short8 a[2], b[4];
#pragma unroll
        for (int rf = 0; rf < 2; ++rf)
          a[rf] = *(const short8*)(Ab + arow[rf] * 64 + ((gg ^ (arow[rf] & 7)) << 3));
#pragma unroll
        for (int cf = 0; cf < 4; ++cf)
          b[cf] = *(const short8*)(Bb + brow[cf] * 64 + ((gg ^ (brow[cf] & 7)) << 3));
#pragma unroll
        for (int rf = 0; rf < 2; ++rf)
#pragma unroll
          for (int cf = 0; cf < 4; ++cf)
            acc[rf][cf] = __builtin_amdgcn_mfma_f32_16x16x32_bf16(a[rf], b[cf], acc[rf][cf], 0, 0, 0);
      }
      // single barrier per kc: after my stage-loads landed (vmcnt) and my
      // ds_reads retired (lgkm), the barrier proves buf[cur^1] is ready for
      // all AND buf[cur] is safe to overwrite next iteration.
      asm volatile("s_waitcnt vmcnt(0) lgkmcnt(0)" ::: "memory");
      __builtin_amdgcn_s_barrier();
      asm volatile("" ::: "memory");
      cur ^= 1;
    }

    float c0[4], c1[4];
#pragma unroll
    for (int i = 0; i < 4; ++i) {
      c0[i] = (PASS == 1) ? INF : 0.f;
      c1[i] = (PASS == 1) ? -INF : 0.f;
    }

#pragma unroll
    for (int rf = 0; rf < 2; ++rf) {
#pragma unroll
      for (int r = 0; r < 4; ++r) {
        const int ri = wr + rf * 16 + quad * 4 + r;
        const int lr = labA[ri];
        float tRn = 0.f, tRx = 0.f;
        if (PASS == 2) { tRn = tA0[ri]; tRx = tA1[ri]; }
#pragma unroll
        for (int cf = 0; cf < 4; ++cf) {
          float sim = acc[rf][cf][r];
          bool same = (lr == labc[cf]);
          bool posok = same && (sim < ONE_EPS);
          if (PASS == 1) {
            float pc = posok ? sim : INF;
            float nc = same ? -INF : sim;
            s0[rf * 4 + r] = fminf(s0[rf * 4 + r], pc);
            s1[rf * 4 + r] = fmaxf(s1[rf * 4 + r], nc);
            c0[cf] = fminf(c0[cf], pc);
            c1[cf] = fmaxf(c1[cf], nc);
          } else {
            if (posok) {
              float e = __expf(fmaf(-2.f, sim, 1.f));
              if (sim < tRx)      s0[rf * 4 + r] += e;
              if (sim < tBx[cf])  c0[cf] += e;
            } else if (!same) {
              float e = (sim > 0.22f) ? __expf(fmaf(50.f, sim, -25.f)) : 0.f;
              if (sim > tRn)      s1[rf * 4 + r] += 1e-30f + e;
              if (sim > tBn[cf])  c1[cf] += 1e-30f + e;
            }
          }
        }
      }
    }

    if (!diag) {
#pragma unroll
      for (int cf = 0; cf < 4; ++cf) {
        float v = c0[cf], w = c1[cf];
#pragma unroll
        for (int m = 16; m < 64; m <<= 1) {
          float vv = __shfl_xor(v, m), ww = __shfl_xor(w, m);
          v = (PASS == 1) ? fminf(v, vv) : (v + vv);
          w = (PASS == 1) ? fmaxf(w, ww) : (w + ww);
        }
        if (quad == 0) {
          // 4 row-group partials per (I,off): slot = rowgroup*128 + col.
          // Nontemporal: consumed once by reduce; keep fb resident in L2.
          size_t o = (size_t)(I * CPS + off) * 512 + (size_t)(wr >> 5) * 128 + wc + cf * 16 + l15;
          __builtin_nontemporal_store(v, cp0 + o);
          __builtin_nontemporal_store(w, cp1 + o);
        }
      }
    }
  }

#pragma unroll
  for (int i = 0; i < 8; ++i) {
#pragma unroll
    for (int m = 1; m < 16; m <<= 1) {
      float v = __shfl_xor(s0[i], m), w = __shfl_xor(s1[i], m);
      s0[i] = (PASS == 1) ? fminf(s0[i], v) : (s0[i] + v);
      s1[i] = (PASS == 1) ? fmaxf(s1[i], w) : (s1[i] + w);
    }
  }
  if (l15 == 0) {
#pragma unroll
    for (int rf = 0; rf < 2; ++rf)
#pragma unroll
      for (int r = 0; r < 4; ++r) {
        int ri = wr + rf * 16 + quad * 4 + r;
        size_t o = (size_t)bid * 256 + (size_t)(wc >> 6) * 128 + ri;
        __builtin_nontemporal_store(s0[rf * 4 + r], rp0 + o);
        __builtin_nontemporal_store(s1[rf * 4 + r], rp1 + o);
      }
  }
}

// ---------------- reduce body (512 threads, 4 partial groups) ---------------
template <int PASS>
__device__ __forceinline__ void reduce_body(
    int T, const float* __restrict__ rp0, const float* __restrict__ rp1,
    const float* __restrict__ cp0, const float* __restrict__ cp1,
    float* __restrict__ o0, float* __restrict__ o1, float* __restrict__ out,
    float* sA, float* sB, float* sred) {
  const int q  = threadIdx.x & 127;     // row within strip
  const int h4 = threadIdx.x >> 7;      // partial stream 0..3

  float a = (PASS == 1) ? __builtin_inff() : 0.f;
  float b = (PASS == 1) ? -__builtin_inff() : 0.f;
  // rp: 8 groups x 2 col-halves = 16 partials; stream h4 takes 4.
#pragma unroll
  for (int g = 0; g < 4; ++g) {
    int c = h4 * 4 + g;                 // 0..15
    int gg = c >> 1, half = c & 1;
    size_t o = (size_t)(T * GPS + gg) * 256 + (size_t)half * 128 + q;
    float v0 = rp0[o], v1 = rp1[o];
    a = (PASS == 1) ? fminf(a, v0) : (a + v0);
    b = (PASS == 1) ? fmaxf(b, v1) : (b + v1);
  }
  // cp: per off, 4 row-group partials; stream h4 takes rowgroup h4.
#pragma unroll
  for (int off = 1; off <= 31; ++off) {
    int Is = (T - off) & 63;
    size_t o = (size_t)(Is * CPS + off) * 512 + (size_t)h4 * 128 + q;
    float v0 = cp0[o], v1 = cp1[o];
    a = (PASS == 1) ? fminf(a, v0) : (a + v0);
    b = (PASS == 1) ? fmaxf(b, v1) : (b + v1);
  }
  if (T >= 32) {
    int Is = T - 32;
    size_t o = (size_t)(Is * CPS + 32) * 512 + (size_t)h4 * 128 + q;
    float v0 = cp0[o], v1 = cp1[o];
    a = (PASS == 1) ? fminf(a, v0) : (a + v0);
    b = (PASS == 1) ? fmaxf(b, v1) : (b + v1);
  }
  if (h4 > 0) { sA[(h4 - 1) * 128 + q] = a; sB[(h4 - 1) * 128 + q] = b; }
  __syncthreads();
  if (h4 == 0) {
#pragma unroll
    for (int p = 0; p < 3; ++p) {
      float v0 = sA[p * 128 + q], v1 = sB[p * 128 + q];
      a = (PASS == 1) ? fminf(a, v0) : (a + v0);
      b = (PASS == 1) ? fmaxf(b, v1) : (b + v1);
    }
    if (PASS == 1) {
      o0[T * 128 + q] = a - 0.1f;
      o1[T * 128 + q] = b + 0.1f;
    } else {
      float loss = 0.f, cnt = 0.f;
      if (a > 0.f && b > 0.f) {
        loss = 0.5f * log1pf(a) + 0.02f * log1pf(b);
        cnt = 1.f;
      }
#pragma unroll
      for (int m = 1; m < 64; m <<= 1) {
        loss += __shfl_xor(loss, m);
        cnt  += __shfl_xor(cnt, m);
      }
      int wv = threadIdx.x >> 6, ln = threadIdx.x & 63;  // waves 0,1 only
      if (ln == 0) { sred[wv] = loss; sred[4 + wv] = cnt; }
    }
  }
  if (PASS == 2) {
    __syncthreads();
    if (threadIdx.x == 0) {
      float L = sred[0] + sred[1];
      float C = sred[4] + sred[5];
      atomicAdd(out, L / 8192.0f);
      atomicAdd(out + 1, -C / 8192.0f);
    }
  }
}

// ---------------- fused cooperative kernel ---------------------------------
// (512, 4): 4 waves/EU -> 2 blocks/CU (8-wave blocks) -> VGPR cap 128.
// Per-thread state ~96 (32 AGPR acc + ~64 arch) -> fits (R14: no spill).
// LDS: 2x(16K+16K) = 64KB + aux ~2.6KB -> 2 blocks/CU (133KB <= 160KB).
__global__ __launch_bounds__(BT, 4)
void mega_kernel(const float* feats, const int* labels, unsigned short* fb,
                 float* rp0, float* rp1, float* cp0, float* cp1,
                 float* tmn, float* tmx, float* out) {
  __shared__ __align__(16) short As[2 * CHUNK_SH];
  __shared__ __align__(16) short Bs[2 * CHUNK_SH];
  __shared__ int   labA[BM];
  __shared__ float tA0[BM], tA1[BM];

  cg::grid_group grid = cg::this_grid();
  const int bid = blockIdx.x;
  const int tid = threadIdx.x;

  // phase 0: convert fp32 -> bf16 (+ init out)
  const int n4 = 8192 * D / 4;
  for (int i = bid * BT + tid; i < n4; i += NPB * BT) {
    float4 v = ((const float4*)feats)[i];
    unsigned lo = f2bf(v.x) | (f2bf(v.y) << 16);
    unsigned hi = f2bf(v.z) | (f2bf(v.w) << 16);
    ((uint2*)fb)[i] = make_uint2(lo, hi);
  }
  if (bid == 0 && tid == 0) { out[0] = 0.f; out[1] = 1.f; }
  __threadfence();
  grid.sync();

  // phase 1: pass1
  pair_body<1>(bid, fb, labels, nullptr, nullptr, rp0, rp1, cp0, cp1,
               As, Bs, labA, tA0, tA1);
  __threadfence();
  grid.sync();

  // phase 2: reduce1 -> thresholds
  if (bid < NT)
    reduce_body<1>(bid, rp0, rp1, cp0, cp1, tmn, tmx, out,
                   (float*)As, (float*)As + 384, (float*)As + 768);
  __threadfence();
  grid.sync();

  // phase 3: pass2
  pair_body<2>(bid, fb, labels, tmn, tmx, rp0, rp1, cp0, cp1,
               As, Bs, labA, tA0, tA1);
  __threadfence();
  grid.sync();

  // phase 4: reduce2 + finalize (atomics onto out)
  if (bid < NT)
    reduce_body<2>(bid, rp0, rp1, cp0, cp1, nullptr, nullptr, out,
                   (float*)As, (float*)As + 384, (float*)As + 768);
}

// ---------------- fallback split kernels -----------------------------------
__global__ void convert_kernel(const float* __restrict__ feats,
                               unsigned short* __restrict__ fb, int n4,
                               float* __restrict__ out) {
  int i = blockIdx.x * blockDim.x + threadIdx.x;
  if (i < n4) {
    float4 v = ((const float4*)feats)[i];
    unsigned lo = f2bf(v.x) | (f2bf(v.y) << 16);
    unsigned hi = f2bf(v.z) | (f2bf(v.w) << 16);
    ((uint2*)fb)[i] = make_uint2(lo, hi);
  }
  if (blockIdx.x == 0 && threadIdx.x == 0) { out[0] = 0.f; out[1] = 1.f; }
}

template <int PASS>
__global__ __launch_bounds__(BT, 4)
void pair_kernel(const unsigned short* __restrict__ fb, const int* __restrict__ labels,
                 const float* __restrict__ tmn, const float* __restrict__ tmx,
                 float* __restrict__ rp0, float* __restrict__ rp1,
                 float* __restrict__ cp0, float* __restrict__ cp1) {
  __shared__ __align__(16) short As[2 * CHUNK_SH];
  __shared__ __align__(16) short Bs[2 * CHUNK_SH];
  __shared__ int   labA[BM];
  __shared__ float tA0[BM], tA1[BM];
  pair_body<PASS>(blockIdx.x, fb, labels, tmn, tmx, rp0, rp1, cp0, cp1,
                  As, Bs, labA, tA0, tA1);
}

template <int PASS>
__global__ void reduce_kernel(const float* __restrict__ rp0, const float* __restrict__ rp1,
                              const float* __restrict__ cp0, const float* __restrict__ cp1,
                              float* __restrict__ o0, float* __restrict__ o1,
                              float* __restrict__ out) {
  __shared__ float sA[384], sB[384], sred[8];
  reduce_body<PASS>(blockIdx.x, rp0, rp1, cp0, cp1, o0, o1, out, sA, sB, sred);
}

extern "C" void kernel_launch(void* const* d_in, const int* in_sizes, int n_in,
                              void* d_out, int out_size, void* d_ws, size_t ws_size,
                              hipStream_t stream) {
  const float* feats  = (const float*)d_in[0];
  const int*   labels = (const int*)d_in[1];
  const int Bn = in_sizes[1];          // 8192
  float* out = (float*)d_out;

  unsigned short* fb = (unsigned short*)d_ws;                       // 4 MB
  float* rp0 = (float*)((char*)d_ws + (size_t)Bn * D * 2);
  float* rp1 = rp0 + (size_t)NPB * 256;
  float* cp0 = rp1 + (size_t)NPB * 256;
  float* cp1 = cp0 + (size_t)NT * CPS * 512;
  float* tmn = cp1 + (size_t)NT * CPS * 512;
  float* tmx = tmn + Bn;

  bool launched = false;
  int maxb = 0;
  hipError_t qe = hipOccupancyMaxActiveBlocksPerMultiprocessor(
      &maxb, (const void*)mega_kernel, BT, 0);
  if (qe == hipSuccess && maxb * 256 >= NPB) {
    void* args[] = {(void*)&feats, (void*)&labels, (void*)&fb,
                    (void*)&rp0, (void*)&rp1, (void*)&cp0, (void*)&cp1,
                    (void*)&tmn, (void*)&tmx, (void*)&out};
    hipError_t le = hipLaunchCooperativeKernel(
        (const void*)mega_kernel, dim3(NPB), dim3(BT), args, 0, stream);
    launched = (le == hipSuccess);
  }
  if (!launched) {
    int n4 = Bn * D / 4;
    convert_kernel<<<(n4 + 255) / 256, 256, 0, stream>>>(feats, fb, n4, out);
    pair_kernel<1><<<NPB, BT, 0, stream>>>(fb, labels, nullptr, nullptr, rp0, rp1, cp0, cp1);
    reduce_kernel<1><<<NT, BT, 0, stream>>>(rp0, rp1, cp0, cp1, tmn, tmx, out);
    pair_kernel<2><<<NPB, BT, 0, stream>>>(fb, labels, tmn, tmx, rp0, rp1, cp0, cp1);
    reduce_kernel<2><<<NT, BT, 0, stream>>>(rp0, rp1, cp0, cp1, nullptr, nullptr, out);
  }
}

// Round 7
// 148.618 us; speedup vs baseline: 1.0291x; 1.0291x over previous
//
#include <hip/hip_runtime.h>
#include <hip/hip_cooperative_groups.h>
#include <stdint.h>

namespace cg = cooperative_groups;

// ---------------------------------------------------------------------------
// Speaker pairwise loss. R16 = R14 (145.0us proven: 8-wave blocks, 32x64
// per-wave tiles, 16 waves/CU, two-barrier counted-vmcnt dbuf, no spill)
// + XCD-chunked block swizzle + epilogue-operand hoist.
// R15 lessons (152.9us, reverted here): nontemporal rp/cp stores pushed
// reduce re-reads to HBM (FETCH 135->196MB, WRITE 39->58MB); the single-
// barrier loop shrank prefetch cover from a full iteration to one compute
// phase. Both reverted to R14 form.
// R16's new lever: R14's FETCH 135MB vs ~45MB compulsory = ~90MB of fb
// re-fetch. Cause: bid=8I+g round-robins across XCDs, so every XCD needs
// ALL 64 strips of fb (4MB) in its 4MB L2 + rp/cp write-allocate -> evict.
// Swizzle pb=(bid&7)*64+bid/8 (bijective): XCD x hosts strips [8x,8x+8) ->
// working set = 41 col-strips = 2.6MB < 4MB L2 -> fb L2-resident (T1).
// Epilogue operands (labels/tmn/tmx) hoisted above the kc loop (loop-
// invariant; latency hides under GEMM). Math/layout/K-order identical.
// ws: fb bf16[B*D] | rp0/rp1[512*256] | cp0/cp1[64*33*512] | tmn[B] tmx[B]
// ---------------------------------------------------------------------------

typedef __attribute__((ext_vector_type(8))) short short8;   // 8 bf16
typedef __attribute__((ext_vector_type(4))) float floatx4;  // MFMA C/D

constexpr int D = 256;
constexpr int BM = 128;
constexpr int NT = 64;                    // 8192/128 strips
constexpr int GPS = 8;                    // groups per strip
constexpr int NPB = NT * GPS;             // 512 pair blocks
constexpr int CPS = 33;                   // cp slots per strip (off 0..32)
constexpr int BT = 512;                   // block threads (8 waves)
constexpr int CHUNK_SH = BM * 64;         // 8192 shorts = 16KB per buffer

__device__ __forceinline__ unsigned f2bf(float f) {  // fp32 -> bf16, RNE
  unsigned u = __float_as_uint(f);
  return (u + 0x7FFFu + ((u >> 16) & 1u)) >> 16;
}

__device__ __forceinline__ void gl_lds16(const void* g, void* l) {
  __builtin_amdgcn_global_load_lds(
      (const __attribute__((address_space(1))) unsigned int*)g,
      (__attribute__((address_space(3))) unsigned int*)l, 16, 0, 0);
}

// XCD-chunked bijective swizzle: hardware bid b lands on XCD b%8; logical
// block pb=(b%8)*64+b/8 gives XCD x the 64 consecutive logical blocks
// [64x, 64x+64) = strips [8x, 8x+8) -> 2.6MB fb working set per XCD L2.
__device__ __forceinline__ int xcd_swz(int b) {
  return ((b & 7) << 6) | (b >> 3);
}

// ---------------- pair body (R14 structure, hoisted epilogue operands) ------
template <int PASS>
__device__ __forceinline__ void pair_body(
    int bid, const unsigned short* __restrict__ fb, const int* __restrict__ labels,
    const float* __restrict__ tmn, const float* __restrict__ tmx,
    float* __restrict__ rp0, float* __restrict__ rp1,
    float* __restrict__ cp0, float* __restrict__ cp1,
    short* As, short* Bs, int* labA, float* tA0, float* tA1) {
  const int I   = bid >> 3;
  const int g   = bid & 7;
  const int nT  = (I < 32) ? 33 : 32;
  const int t0  = (g * nT) >> 3;
  const int t1  = ((g + 1) * nT) >> 3;
  const int row0 = I * BM;

  const int tid  = threadIdx.x;
  const int lane = tid & 63;
  const int wave = tid >> 6;               // 0..7
  const int l15  = lane & 15;
  const int quad = lane >> 4;
  const int wr   = (wave >> 1) * 32;       // row offset: 0,32,64,96
  const int wc   = (wave & 1) * 64;        // col offset: 0,64

  const float ONE_EPS = 1.0f - 1e-5f;
  const float INF = __builtin_inff();

  __syncthreads();                       // protect smem vs previous phase
  if (tid < BM) {
    labA[tid] = labels[row0 + tid];
    if (PASS == 2) { tA0[tid] = tmn[row0 + tid]; tA1[tid] = tmx[row0 + tid]; }
  }

  // Stage one 64-col chunk of A-strip + column-strip into LDS buffer b.
  // Linear LDS dest (gl_lds constraint); XOR swizzle on GLOBAL source:
  // slot sl of row r holds global col-block sl^(r&7) (proven 0-conflict).
  auto stage = [&](int b, int col0, int kc) {
#pragma unroll
    for (int j = 0; j < 2; ++j) {
      int idx = j * BT + tid;            // 0..1023
      int r   = idx >> 3;                // row 0..127
      int sl  = idx & 7;                 // 16B slot within 128B row
      int cb  = sl ^ (r & 7);
      const char* ga = (const char*)fb + (((size_t)(row0 + r)) << 9) + (kc << 7) + (cb << 4);
      const char* gb = (const char*)fb + (((size_t)(col0 + r)) << 9) + (kc << 7) + (cb << 4);
      gl_lds16(ga, (char*)As + (size_t)b * (CHUNK_SH * 2) + ((size_t)idx << 4));
      gl_lds16(gb, (char*)Bs + (size_t)b * (CHUNK_SH * 2) + ((size_t)idx << 4));
    }
  };

  int arow[2], brow[4];
#pragma unroll
  for (int i = 0; i < 2; ++i) arow[i] = wr + i * 16 + l15;
#pragma unroll
  for (int i = 0; i < 4; ++i) brow[i] = wc + i * 16 + l15;

  float s0[8], s1[8];
#pragma unroll
  for (int i = 0; i < 8; ++i) {
    s0[i] = (PASS == 1) ? INF : 0.f;
    s1[i] = (PASS == 1) ? -INF : 0.f;
  }

  stage(0, ((I + t0) & 63) * BM, 0);     // prologue

  int cur = 0;
  for (int off = t0; off < t1; ++off) {
    const int J = (I + off) & 63;
    const int col0 = J * BM;
    const bool diag = (off == 0);

    // hoisted epilogue operands: loop-invariant over kc; latency hides
    // under the GEMM below.
    int labc[4];
    float tBn[4], tBx[4];
#pragma unroll
    for (int cf = 0; cf < 4; ++cf) {
      int ci = col0 + wc + cf * 16 + l15;
      labc[cf] = labels[ci];
      if (PASS == 2) { tBn[cf] = tmn[ci]; tBx[cf] = tmx[ci]; }
    }

    floatx4 acc[2][4];
#pragma unroll
    for (int rf = 0; rf < 2; ++rf)
#pragma unroll
      for (int cf = 0; cf < 4; ++cf)
        acc[rf][cf] = (floatx4)(0.f);

#pragma unroll
    for (int kc = 0; kc < 4; ++kc) {
      if (kc < 3) {
        stage(cur ^ 1, col0, kc + 1);
        asm volatile("s_waitcnt vmcnt(4)" ::: "memory");
      } else if (off + 1 < t1) {
        stage(cur ^ 1, ((I + off + 1) & 63) * BM, 0);
        asm volatile("s_waitcnt vmcnt(4)" ::: "memory");
      } else {
        asm volatile("s_waitcnt vmcnt(0)" ::: "memory");
      }
      __builtin_amdgcn_s_barrier();          // data-ready barrier
      asm volatile("" ::: "memory");

      const short* Ab = As + cur * CHUNK_SH;
      const short* Bb = Bs + cur * CHUNK_SH;
#pragma unroll
      for (int ks = 0; ks < 2; ++ks) {
        const int gg = ks * 4 + quad;
        short8 a[2], b[4];
#pragma unroll
        for (int rf = 0; rf < 2; ++rf)
          a[rf] = *(const short8*)(Ab + arow[rf] * 64 + ((gg ^ (arow[rf] & 7)) << 3));
#pragma unroll
        for (int cf = 0; cf < 4; ++cf)
          b[cf] = *(const short8*)(Bb + brow[cf] * 64 + ((gg ^ (brow[cf] & 7)) << 3));
#pragma unroll
        for (int rf = 0; rf < 2; ++rf)
#pragma unroll
          for (int cf = 0; cf < 4; ++cf)
            acc[rf][cf] = __builtin_amdgcn_mfma_f32_16x16x32_bf16(a[rf], b[cf], acc[rf][cf], 0, 0, 0);
      }
      asm volatile("s_waitcnt lgkmcnt(0)" ::: "memory");
      __builtin_amdgcn_s_barrier();          // buffer-free barrier
      asm volatile("" ::: "memory");
      cur ^= 1;
    }

    float c0[4], c1[4];
#pragma unroll
    for (int i = 0; i < 4; ++i) {
      c0[i] = (PASS == 1) ? INF : 0.f;
      c1[i] = (PASS == 1) ? -INF : 0.f;
    }

#pragma unroll
    for (int rf = 0; rf < 2; ++rf) {
#pragma unroll
      for (int r = 0; r < 4; ++r) {
        const int ri = wr + rf * 16 + quad * 4 + r;
        const int lr = labA[ri];
        float tRn = 0.f, tRx = 0.f;
        if (PASS == 2) { tRn = tA0[ri]; tRx = tA1[ri]; }
#pragma unroll
        for (int cf = 0; cf < 4; ++cf) {
          float sim = acc[rf][cf][r];
          bool same = (lr == labc[cf]);
          bool posok = same && (sim < ONE_EPS);
          if (PASS == 1) {
            float pc = posok ? sim : INF;
            float nc = same ? -INF : sim;
            s0[rf * 4 + r] = fminf(s0[rf * 4 + r], pc);
            s1[rf * 4 + r] = fmaxf(s1[rf * 4 + r], nc);
            c0[cf] = fminf(c0[cf], pc);
            c1[cf] = fmaxf(c1[cf], nc);
          } else {
            if (posok) {
              float e = __expf(fmaf(-2.f, sim, 1.f));
              if (sim < tRx)      s0[rf * 4 + r] += e;
              if (sim < tBx[cf])  c0[cf] += e;
            } else if (!same) {
              float e = (sim > 0.22f) ? __expf(fmaf(50.f, sim, -25.f)) : 0.f;
              if (sim > tRn)      s1[rf * 4 + r] += 1e-30f + e;
              if (sim > tBn[cf])  c1[cf] += 1e-30f + e;
            }
          }
        }
      }
    }

    if (!diag) {
#pragma unroll
      for (int cf = 0; cf < 4; ++cf) {
        float v = c0[cf], w = c1[cf];
#pragma unroll
        for (int m = 16; m < 64; m <<= 1) {
          float vv = __shfl_xor(v, m), ww = __shfl_xor(w, m);
          v = (PASS == 1) ? fminf(v, vv) : (v + vv);
          w = (PASS == 1) ? fmaxf(w, ww) : (w + ww);
        }
        if (quad == 0) {
          // 4 row-group partials per (I,off): slot = rowgroup*128 + col
          size_t o = (size_t)(I * CPS + off) * 512 + (size_t)(wr >> 5) * 128 + wc + cf * 16 + l15;
          cp0[o] = v;
          cp1[o] = w;
        }
      }
    }
  }

#pragma unroll
  for (int i = 0; i < 8; ++i) {
#pragma unroll
    for (int m = 1; m < 16; m <<= 1) {
      float v = __shfl_xor(s0[i], m), w = __shfl_xor(s1[i], m);
      s0[i] = (PASS == 1) ? fminf(s0[i], v) : (s0[i] + v);
      s1[i] = (PASS == 1) ? fmaxf(s1[i], w) : (s1[i] + w);
    }
  }
  if (l15 == 0) {
#pragma unroll
    for (int rf = 0; rf < 2; ++rf)
#pragma unroll
      for (int r = 0; r < 4; ++r) {
        int ri = wr + rf * 16 + quad * 4 + r;
        size_t o = (size_t)bid * 256 + (size_t)(wc >> 6) * 128 + ri;
        rp0[o] = s0[rf * 4 + r];
        rp1[o] = s1[rf * 4 + r];
      }
  }
}

// ---------------- reduce body (512 threads, 4 partial groups) ---------------
template <int PASS>
__device__ __forceinline__ void reduce_body(
    int T, const float* __restrict__ rp0, const float* __restrict__ rp1,
    const float* __restrict__ cp0, const float* __restrict__ cp1,
    float* __restrict__ o0, float* __restrict__ o1, float* __restrict__ out,
    float* sA, float* sB, float* sred) {
  const int q  = threadIdx.x & 127;     // row within strip
  const int h4 = threadIdx.x >> 7;      // partial stream 0..3

  float a = (PASS == 1) ? __builtin_inff() : 0.f;
  float b = (PASS == 1) ? -__builtin_inff() : 0.f;
  // rp: 8 groups x 2 col-halves = 16 partials; stream h4 takes 4.
#pragma unroll
  for (int g = 0; g < 4; ++g) {
    int c = h4 * 4 + g;                 // 0..15
    int gg = c >> 1, half = c & 1;
    size_t o = (size_t)(T * GPS + gg) * 256 + (size_t)half * 128 + q;
    float v0 = rp0[o], v1 = rp1[o];
    a = (PASS == 1) ? fminf(a, v0) : (a + v0);
    b = (PASS == 1) ? fmaxf(b, v1) : (b + v1);
  }
  // cp: per off, 4 row-group partials; stream h4 takes rowgroup h4.
#pragma unroll
  for (int off = 1; off <= 31; ++off) {
    int Is = (T - off) & 63;
    size_t o = (size_t)(Is * CPS + off) * 512 + (size_t)h4 * 128 + q;
    float v0 = cp0[o], v1 = cp1[o];
    a = (PASS == 1) ? fminf(a, v0) : (a + v0);
    b = (PASS == 1) ? fmaxf(b, v1) : (b + v1);
  }
  if (T >= 32) {
    int Is = T - 32;
    size_t o = (size_t)(Is * CPS + 32) * 512 + (size_t)h4 * 128 + q;
    float v0 = cp0[o], v1 = cp1[o];
    a = (PASS == 1) ? fminf(a, v0) : (a + v0);
    b = (PASS == 1) ? fmaxf(b, v1) : (b + v1);
  }
  if (h4 > 0) { sA[(h4 - 1) * 128 + q] = a; sB[(h4 - 1) * 128 + q] = b; }
  __syncthreads();
  if (h4 == 0) {
#pragma unroll
    for (int p = 0; p < 3; ++p) {
      float v0 = sA[p * 128 + q], v1 = sB[p * 128 + q];
      a = (PASS == 1) ? fminf(a, v0) : (a + v0);
      b = (PASS == 1) ? fmaxf(b, v1) : (b + v1);
    }
    if (PASS == 1) {
      o0[T * 128 + q] = a - 0.1f;
      o1[T * 128 + q] = b + 0.1f;
    } else {
      float loss = 0.f, cnt = 0.f;
      if (a > 0.f && b > 0.f) {
        loss = 0.5f * log1pf(a) + 0.02f * log1pf(b);
        cnt = 1.f;
      }
#pragma unroll
      for (int m = 1; m < 64; m <<= 1) {
        loss += __shfl_xor(loss, m);
        cnt  += __shfl_xor(cnt, m);
      }
      int wv = threadIdx.x >> 6, ln = threadIdx.x & 63;  // waves 0,1 only
      if (ln == 0) { sred[wv] = loss; sred[4 + wv] = cnt; }
    }
  }
  if (PASS == 2) {
    __syncthreads();
    if (threadIdx.x == 0) {
      float L = sred[0] + sred[1];
      float C = sred[4] + sred[5];
      atomicAdd(out, L / 8192.0f);
      atomicAdd(out + 1, -C / 8192.0f);
    }
  }
}

// ---------------- fused cooperative kernel ---------------------------------
// (512, 4): 4 waves/EU -> 2 blocks/CU (8-wave blocks) -> VGPR cap 128.
// Per-thread state ~96 (32 AGPR acc + ~64 arch) -> fits (R14: no spill).
// LDS: 2x(16K+16K) = 64KB + aux ~2.6KB -> 2 blocks/CU (133KB <= 160KB).
__global__ __launch_bounds__(BT, 4)
void mega_kernel(const float* feats, const int* labels, unsigned short* fb,
                 float* rp0, float* rp1, float* cp0, float* cp1,
                 float* tmn, float* tmx, float* out) {
  __shared__ __align__(16) short As[2 * CHUNK_SH];
  __shared__ __align__(16) short Bs[2 * CHUNK_SH];
  __shared__ int   labA[BM];
  __shared__ float tA0[BM], tA1[BM];

  cg::grid_group grid = cg::this_grid();
  const int bid = blockIdx.x;
  const int pb  = xcd_swz(bid);          // XCD-chunked logical block id
  const int tid = threadIdx.x;

  // phase 0: convert fp32 -> bf16 (+ init out)
  const int n4 = 8192 * D / 4;
  for (int i = bid * BT + tid; i < n4; i += NPB * BT) {
    float4 v = ((const float4*)feats)[i];
    unsigned lo = f2bf(v.x) | (f2bf(v.y) << 16);
    unsigned hi = f2bf(v.z) | (f2bf(v.w) << 16);
    ((uint2*)fb)[i] = make_uint2(lo, hi);
  }
  if (bid == 0 && tid == 0) { out[0] = 0.f; out[1] = 1.f; }
  __threadfence();
  grid.sync();

  // phase 1: pass1
  pair_body<1>(pb, fb, labels, nullptr, nullptr, rp0, rp1, cp0, cp1,
               As, Bs, labA, tA0, tA1);
  __threadfence();
  grid.sync();

  // phase 2: reduce1 -> thresholds
  if (bid < NT)
    reduce_body<1>(bid, rp0, rp1, cp0, cp1, tmn, tmx, out,
                   (float*)As, (float*)As + 384, (float*)As + 768);
  __threadfence();
  grid.sync();

  // phase 3: pass2
  pair_body<2>(pb, fb, labels, tmn, tmx, rp0, rp1, cp0, cp1,
               As, Bs, labA, tA0, tA1);
  __threadfence();
  grid.sync();

  // phase 4: reduce2 + finalize (atomics onto out)
  if (bid < NT)
    reduce_body<2>(bid, rp0, rp1, cp0, cp1, nullptr, nullptr, out,
                   (float*)As, (float*)As + 384, (float*)As + 768);
}

// ---------------- fallback split kernels -----------------------------------
__global__ void convert_kernel(const float* __restrict__ feats,
                               unsigned short* __restrict__ fb, int n4,
                               float* __restrict__ out) {
  int i = blockIdx.x * blockDim.x + threadIdx.x;
  if (i < n4) {
    float4 v = ((const float4*)feats)[i];
    unsigned lo = f2bf(v.x) | (f2bf(v.y) << 16);
    unsigned hi = f2bf(v.z) | (f2bf(v.w) << 16);
    ((uint2*)fb)[i] = make_uint2(lo, hi);
  }
  if (blockIdx.x == 0 && threadIdx.x == 0) { out[0] = 0.f; out[1] = 1.f; }
}

template <int PASS>
__global__ __launch_bounds__(BT, 4)
void pair_kernel(const unsigned short* __restrict__ fb, const int* __restrict__ labels,
                 const float* __restrict__ tmn, const float* __restrict__ tmx,
                 float* __restrict__ rp0, float* __restrict__ rp1,
                 float* __restrict__ cp0, float* __restrict__ cp1) {
  __shared__ __align__(16) short As[2 * CHUNK_SH];
  __shared__ __align__(16) short Bs[2 * CHUNK_SH];
  __shared__ int   labA[BM];
  __shared__ float tA0[BM], tA1[BM];
  pair_body<PASS>(xcd_swz((int)blockIdx.x), fb, labels, tmn, tmx,
                  rp0, rp1, cp0, cp1, As, Bs, labA, tA0, tA1);
}

template <int PASS>
__global__ void reduce_kernel(const float* __restrict__ rp0, const float* __restrict__ rp1,
                              const float* __restrict__ cp0, const float* __restrict__ cp1,
                              float* __restrict__ o0, float* __restrict__ o1,
                              float* __restrict__ out) {
  __shared__ float sA[384], sB[384], sred[8];
  reduce_body<PASS>(blockIdx.x, rp0, rp1, cp0, cp1, o0, o1, out, sA, sB, sred);
}

extern "C" void kernel_launch(void* const* d_in, const int* in_sizes, int n_in,
                              void* d_out, int out_size, void* d_ws, size_t ws_size,
                              hipStream_t stream) {
  const float* feats  = (const float*)d_in[0];
  const int*   labels = (const int*)d_in[1];
  const int Bn = in_sizes[1];          // 8192
  float* out = (float*)d_out;

  unsigned short* fb = (unsigned short*)d_ws;                       // 4 MB
  float* rp0 = (float*)((char*)d_ws + (size_t)Bn * D * 2);
  float* rp1 = rp0 + (size_t)NPB * 256;
  float* cp0 = rp1 + (size_t)NPB * 256;
  float* cp1 = cp0 + (size_t)NT * CPS * 512;
  float* tmn = cp1 + (size_t)NT * CPS * 512;
  float* tmx = tmn + Bn;

  bool launched = false;
  int maxb = 0;
  hipError_t qe = hipOccupancyMaxActiveBlocksPerMultiprocessor(
      &maxb, (const void*)mega_kernel, BT, 0);
  if (qe == hipSuccess && maxb * 256 >= NPB) {
    void* args[] = {(void*)&feats, (void*)&labels, (void*)&fb,
                    (void*)&rp0, (void*)&rp1, (void*)&cp0, (void*)&cp1,
                    (void*)&tmn, (void*)&tmx, (void*)&out};
    hipError_t le = hipLaunchCooperativeKernel(
        (const void*)mega_kernel, dim3(NPB), dim3(BT), args, 0, stream);
    launched = (le == hipSuccess);
  }
  if (!launched) {
    int n4 = Bn * D / 4;
    convert_kernel<<<(n4 + 255) / 256, 256, 0, stream>>>(feats, fb, n4, out);
    pair_kernel<1><<<NPB, BT, 0, stream>>>(fb, labels, nullptr, nullptr, rp0, rp1, cp0, cp1);
    reduce_kernel<1><<<NT, BT, 0, stream>>>(rp0, rp1, cp0, cp1, tmn, tmx, out);
    pair_kernel<2><<<NPB, BT, 0, stream>>>(fb, labels, tmn, tmx, rp0, rp1, cp0, cp1);
    reduce_kernel<2><<<NT, BT, 0, stream>>>(rp0, rp1, cp0, cp1, nullptr, nullptr, out);
  }
}

// Round 8
// 140.385 us; speedup vs baseline: 1.0894x; 1.0586x over previous
//
#include <hip/hip_runtime.h>
#include <hip/hip_cooperative_groups.h>
#include <stdint.h>

namespace cg = cooperative_groups;

// ---------------------------------------------------------------------------
// Speaker pairwise loss. R17. Best so far: R14 = 145.0us (8-wave blocks,
// 32x64/wave, 16 waves/CU, two-barrier counted-vmcnt dbuf, no spill).
// R15 (NT rp/cp + 1-barrier) 152.9 REGR; R16 (XCD swizzle) FETCH 135->65MB
// exactly as predicted but dur 148.6 -> pair passes are NOT memory-bound;
// residual is the lockstep schedule. Counter-derived busy: MFMA 13.8us,
// VALU 29.5us, LDS ~32us vs ~128us pair time.
// R17 removes HALF the GEMM work instead of scheduling it better: pass1
// STORES the sim tiles (f32, bitwise) to ws (138MB, nontemporal, coalesced
// [tile][8][512]xfloat4); pass2 STREAMS them back -> epilogue-only pass2
// (no staging, no barriers, no MFMA; ~22us of HBM reads at 6.3TB/s).
// Values reloaded are bit-identical to recomputation -> absmax 0.0.
// vmcnt note: sim-stores only add OLDER outstanding vmem entries, so the
// counted vmcnt(4) still proves the newest stage loads landed.
// Gate: ws_size >= ~146MB; else fall back to the exact R14-compute variant
// (separate __global__ instantiation -> clean regalloc per path).
// ws: fb 4MB | rp0/rp1 1MB | cp0/cp1 8.65MB | tmn/tmx 64KB | sims 138MB
// ---------------------------------------------------------------------------

typedef __attribute__((ext_vector_type(8))) short short8;   // 8 bf16
typedef __attribute__((ext_vector_type(4))) float floatx4;  // MFMA C/D

constexpr int D = 256;
constexpr int BM = 128;
constexpr int NT = 64;                    // 8192/128 strips
constexpr int GPS = 8;                    // groups per strip
constexpr int NPB = NT * GPS;             // 512 pair blocks
constexpr int CPS = 33;                   // cp slots per strip (off 0..32)
constexpr int BT = 512;                   // block threads (8 waves)
constexpr int CHUNK_SH = BM * 64;         // 8192 shorts = 16KB per buffer
constexpr int TILE_SLOTS = NT * CPS;      // 2112 sim tiles
constexpr size_t TILE_V4 = 8 * BT;        // 4096 float4 per tile (64KB)

__device__ __forceinline__ unsigned f2bf(float f) {  // fp32 -> bf16, RNE
  unsigned u = __float_as_uint(f);
  return (u + 0x7FFFu + ((u >> 16) & 1u)) >> 16;
}

__device__ __forceinline__ void gl_lds16(const void* g, void* l) {
  __builtin_amdgcn_global_load_lds(
      (const __attribute__((address_space(1))) unsigned int*)g,
      (__attribute__((address_space(3))) unsigned int*)l, 16, 0, 0);
}

// ---------------- pair body -------------------------------------------------
// COMPUTE = do the GEMM (pass1 always; pass2 only when not cached).
// PASS==1 && CACHED: additionally store acc tiles to simsv.
// PASS==2 && CACHED: load acc tiles from simsv; no staging/barriers/MFMA.
template <int PASS, bool CACHED>
__device__ __forceinline__ void pair_body(
    int bid, const unsigned short* __restrict__ fb, const int* __restrict__ labels,
    const float* __restrict__ tmn, const float* __restrict__ tmx,
    float* __restrict__ rp0, float* __restrict__ rp1,
    float* __restrict__ cp0, float* __restrict__ cp1,
    floatx4* __restrict__ simsv,
    short* As, short* Bs, int* labA, float* tA0, float* tA1) {
  constexpr bool COMPUTE = (PASS == 1) || !CACHED;

  const int I   = bid >> 3;
  const int g   = bid & 7;
  const int nT  = (I < 32) ? 33 : 32;
  const int t0  = (g * nT) >> 3;
  const int t1  = ((g + 1) * nT) >> 3;
  const int row0 = I * BM;

  const int tid  = threadIdx.x;
  const int lane = tid & 63;
  const int wave = tid >> 6;               // 0..7
  const int l15  = lane & 15;
  const int quad = lane >> 4;
  const int wr   = (wave >> 1) * 32;       // row offset: 0,32,64,96
  const int wc   = (wave & 1) * 64;        // col offset: 0,64

  const float ONE_EPS = 1.0f - 1e-5f;
  const float INF = __builtin_inff();

  __syncthreads();                       // protect smem vs previous phase
  if (tid < BM) {
    labA[tid] = labels[row0 + tid];
    if (PASS == 2) { tA0[tid] = tmn[row0 + tid]; tA1[tid] = tmx[row0 + tid]; }
  }
  if constexpr (!COMPUTE) {
    __syncthreads();                     // no kc-loop barriers in cached path
  }

  // Stage one 64-col chunk of A-strip + column-strip into LDS buffer b.
  // Linear LDS dest (gl_lds constraint); XOR swizzle on GLOBAL source:
  // slot sl of row r holds global col-block sl^(r&7) (proven 0-conflict).
  auto stage = [&](int b, int col0, int kc) {
#pragma unroll
    for (int j = 0; j < 2; ++j) {
      int idx = j * BT + tid;            // 0..1023
      int r   = idx >> 3;                // row 0..127
      int sl  = idx & 7;                 // 16B slot within 128B row
      int cb  = sl ^ (r & 7);
      const char* ga = (const char*)fb + (((size_t)(row0 + r)) << 9) + (kc << 7) + (cb << 4);
      const char* gb = (const char*)fb + (((size_t)(col0 + r)) << 9) + (kc << 7) + (cb << 4);
      gl_lds16(ga, (char*)As + (size_t)b * (CHUNK_SH * 2) + ((size_t)idx << 4));
      gl_lds16(gb, (char*)Bs + (size_t)b * (CHUNK_SH * 2) + ((size_t)idx << 4));
    }
  };

  int arow[2], brow[4];
#pragma unroll
  for (int i = 0; i < 2; ++i) arow[i] = wr + i * 16 + l15;
#pragma unroll
  for (int i = 0; i < 4; ++i) brow[i] = wc + i * 16 + l15;

  float s0[8], s1[8];
#pragma unroll
  for (int i = 0; i < 8; ++i) {
    s0[i] = (PASS == 1) ? INF : 0.f;
    s1[i] = (PASS == 1) ? -INF : 0.f;
  }

  if constexpr (COMPUTE) {
    stage(0, ((I + t0) & 63) * BM, 0);   // prologue
  }

  int cur = 0;
  for (int off = t0; off < t1; ++off) {
    const int J = (I + off) & 63;
    const int col0 = J * BM;
    const bool diag = (off == 0);

    // hoisted epilogue operands: loop-invariant over kc; latency hides
    // under the GEMM / sim loads below.
    int labc[4];
    float tBn[4], tBx[4];
#pragma unroll
    for (int cf = 0; cf < 4; ++cf) {
      int ci = col0 + wc + cf * 16 + l15;
      labc[cf] = labels[ci];
      if (PASS == 2) { tBn[cf] = tmn[ci]; tBx[cf] = tmx[ci]; }
    }

    floatx4 acc[2][4];
    if constexpr (COMPUTE) {
#pragma unroll
      for (int rf = 0; rf < 2; ++rf)
#pragma unroll
        for (int cf = 0; cf < 4; ++cf)
          acc[rf][cf] = (floatx4)(0.f);

#pragma unroll
      for (int kc = 0; kc < 4; ++kc) {
        if (kc < 3) {
          stage(cur ^ 1, col0, kc + 1);
          asm volatile("s_waitcnt vmcnt(4)" ::: "memory");
        } else if (off + 1 < t1) {
          stage(cur ^ 1, ((I + off + 1) & 63) * BM, 0);
          asm volatile("s_waitcnt vmcnt(4)" ::: "memory");
        } else {
          asm volatile("s_waitcnt vmcnt(0)" ::: "memory");
        }
        __builtin_amdgcn_s_barrier();        // data-ready barrier
        asm volatile("" ::: "memory");

        const short* Ab = As + cur * CHUNK_SH;
        const short* Bb = Bs + cur * CHUNK_SH;
#pragma unroll
        for (int ks = 0; ks < 2; ++ks) {
          const int gg = ks * 4 + quad;
          short8 a[2], b[4];
#pragma unroll
          for (int rf = 0; rf < 2; ++rf)
            a[rf] = *(const short8*)(Ab + arow[rf] * 64 + ((gg ^ (arow[rf] & 7)) << 3));
#pragma unroll
          for (int cf = 0; cf < 4; ++cf)
            b[cf] = *(const short8*)(Bb + brow[cf] * 64 + ((gg ^ (brow[cf] & 7)) << 3));
#pragma unroll
          for (int rf = 0; rf < 2; ++rf)
#pragma unroll
            for (int cf = 0; cf < 4; ++cf)
              acc[rf][cf] = __builtin_amdgcn_mfma_f32_16x16x32_bf16(a[rf], b[cf], acc[rf][cf], 0, 0, 0);
        }
        asm volatile("s_waitcnt lgkmcnt(0)" ::: "memory");
        __builtin_amdgcn_s_barrier();        // buffer-free barrier
        asm volatile("" ::: "memory");
        cur ^= 1;
      }
    } else {
      // cached pass2: stream the tile back (bitwise what pass1 computed)
      const floatx4* tp = simsv + (size_t)(I * CPS + off) * TILE_V4;
#pragma unroll
      for (int rf = 0; rf < 2; ++rf)
#pragma unroll
        for (int cf = 0; cf < 4; ++cf)
          acc[rf][cf] = __builtin_nontemporal_load(tp + (size_t)(rf * 4 + cf) * BT + tid);
    }

    if constexpr (PASS == 1 && CACHED) {
      // store the sim tile for pass2 (nontemporal: read once, much later)
      floatx4* tp = simsv + (size_t)(I * CPS + off) * TILE_V4;
#pragma unroll
      for (int rf = 0; rf < 2; ++rf)
#pragma unroll
        for (int cf = 0; cf < 4; ++cf)
          __builtin_nontemporal_store(acc[rf][cf], tp + (size_t)(rf * 4 + cf) * BT + tid);
    }

    float c0[4], c1[4];
#pragma unroll
    for (int i = 0; i < 4; ++i) {
      c0[i] = (PASS == 1) ? INF : 0.f;
      c1[i] = (PASS == 1) ? -INF : 0.f;
    }

#pragma unroll
    for (int rf = 0; rf < 2; ++rf) {
#pragma unroll
      for (int r = 0; r < 4; ++r) {
        const int ri = wr + rf * 16 + quad * 4 + r;
        const int lr = labA[ri];
        float tRn = 0.f, tRx = 0.f;
        if (PASS == 2) { tRn = tA0[ri]; tRx = tA1[ri]; }
#pragma unroll
        for (int cf = 0; cf < 4; ++cf) {
          float sim = acc[rf][cf][r];
          bool same = (lr == labc[cf]);
          bool posok = same && (sim < ONE_EPS);
          if (PASS == 1) {
            float pc = posok ? sim : INF;
            float nc = same ? -INF : sim;
            s0[rf * 4 + r] = fminf(s0[rf * 4 + r], pc);
            s1[rf * 4 + r] = fmaxf(s1[rf * 4 + r], nc);
            c0[cf] = fminf(c0[cf], pc);
            c1[cf] = fmaxf(c1[cf], nc);
          } else {
            if (posok) {
              float e = __expf(fmaf(-2.f, sim, 1.f));
              if (sim < tRx)      s0[rf * 4 + r] += e;
              if (sim < tBx[cf])  c0[cf] += e;
            } else if (!same) {
              float e = (sim > 0.22f) ? __expf(fmaf(50.f, sim, -25.f)) : 0.f;
              if (sim > tRn)      s1[rf * 4 + r] += 1e-30f + e;
              if (sim > tBn[cf])  c1[cf] += 1e-30f + e;
            }
          }
        }
      }
    }

    if (!diag) {
#pragma unroll
      for (int cf = 0; cf < 4; ++cf) {
        float v = c0[cf], w = c1[cf];
#pragma unroll
        for (int m = 16; m < 64; m <<= 1) {
          float vv = __shfl_xor(v, m), ww = __shfl_xor(w, m);
          v = (PASS == 1) ? fminf(v, vv) : (v + vv);
          w = (PASS == 1) ? fmaxf(w, ww) : (w + ww);
        }
        if (quad == 0) {
          // 4 row-group partials per (I,off): slot = rowgroup*128 + col
          size_t o = (size_t)(I * CPS + off) * 512 + (size_t)(wr >> 5) * 128 + wc + cf * 16 + l15;
          cp0[o] = v;
          cp1[o] = w;
        }
      }
    }
  }

#pragma unroll
  for (int i = 0; i < 8; ++i) {
#pragma unroll
    for (int m = 1; m < 16; m <<= 1) {
      float v = __shfl_xor(s0[i], m), w = __shfl_xor(s1[i], m);
      s0[i] = (PASS == 1) ? fminf(s0[i], v) : (s0[i] + v);
      s1[i] = (PASS == 1) ? fmaxf(s1[i], w) : (s1[i] + w);
    }
  }
  if (l15 == 0) {
#pragma unroll
    for (int rf = 0; rf < 2; ++rf)
#pragma unroll
      for (int r = 0; r < 4; ++r) {
        int ri = wr + rf * 16 + quad * 4 + r;
        size_t o = (size_t)bid * 256 + (size_t)(wc >> 6) * 128 + ri;
        rp0[o] = s0[rf * 4 + r];
        rp1[o] = s1[rf * 4 + r];
      }
  }
}

// ---------------- reduce body (512 threads, 4 partial groups) ---------------
template <int PASS>
__device__ __forceinline__ void reduce_body(
    int T, const float* __restrict__ rp0, const float* __restrict__ rp1,
    const float* __restrict__ cp0, const float* __restrict__ cp1,
    float* __restrict__ o0, float* __restrict__ o1, float* __restrict__ out,
    float* sA, float* sB, float* sred) {
  const int q  = threadIdx.x & 127;     // row within strip
  const int h4 = threadIdx.x >> 7;      // partial stream 0..3

  float a = (PASS == 1) ? __builtin_inff() : 0.f;
  float b = (PASS == 1) ? -__builtin_inff() : 0.f;
  // rp: 8 groups x 2 col-halves = 16 partials; stream h4 takes 4.
#pragma unroll
  for (int g = 0; g < 4; ++g) {
    int c = h4 * 4 + g;                 // 0..15
    int gg = c >> 1, half = c & 1;
    size_t o = (size_t)(T * GPS + gg) * 256 + (size_t)half * 128 + q;
    float v0 = rp0[o], v1 = rp1[o];
    a = (PASS == 1) ? fminf(a, v0) : (a + v0);
    b = (PASS == 1) ? fmaxf(b, v1) : (b + v1);
  }
  // cp: per off, 4 row-group partials; stream h4 takes rowgroup h4.
#pragma unroll
  for (int off = 1; off <= 31; ++off) {
    int Is = (T - off) & 63;
    size_t o = (size_t)(Is * CPS + off) * 512 + (size_t)h4 * 128 + q;
    float v0 = cp0[o], v1 = cp1[o];
    a = (PASS == 1) ? fminf(a, v0) : (a + v0);
    b = (PASS == 1) ? fmaxf(b, v1) : (b + v1);
  }
  if (T >= 32) {
    int Is = T - 32;
    size_t o = (size_t)(Is * CPS + 32) * 512 + (size_t)h4 * 128 + q;
    float v0 = cp0[o], v1 = cp1[o];
    a = (PASS == 1) ? fminf(a, v0) : (a + v0);
    b = (PASS == 1) ? fmaxf(b, v1) : (b + v1);
  }
  if (h4 > 0) { sA[(h4 - 1) * 128 + q] = a; sB[(h4 - 1) * 128 + q] = b; }
  __syncthreads();
  if (h4 == 0) {
#pragma unroll
    for (int p = 0; p < 3; ++p) {
      float v0 = sA[p * 128 + q], v1 = sB[p * 128 + q];
      a = (PASS == 1) ? fminf(a, v0) : (a + v0);
      b = (PASS == 1) ? fmaxf(b, v1) : (b + v1);
    }
    if (PASS == 1) {
      o0[T * 128 + q] = a - 0.1f;
      o1[T * 128 + q] = b + 0.1f;
    } else {
      float loss = 0.f, cnt = 0.f;
      if (a > 0.f && b > 0.f) {
        loss = 0.5f * log1pf(a) + 0.02f * log1pf(b);
        cnt = 1.f;
      }
#pragma unroll
      for (int m = 1; m < 64; m <<= 1) {
        loss += __shfl_xor(loss, m);
        cnt  += __shfl_xor(cnt, m);
      }
      int wv = threadIdx.x >> 6, ln = threadIdx.x & 63;  // waves 0,1 only
      if (ln == 0) { sred[wv] = loss; sred[4 + wv] = cnt; }
    }
  }
  if (PASS == 2) {
    __syncthreads();
    if (threadIdx.x == 0) {
      float L = sred[0] + sred[1];
      float C = sred[4] + sred[5];
      atomicAdd(out, L / 8192.0f);
      atomicAdd(out + 1, -C / 8192.0f);
    }
  }
}

// ---------------- fused cooperative kernel ---------------------------------
// (512, 4): 4 waves/EU -> 2 blocks/CU (8-wave blocks) -> VGPR cap 128.
// Per-thread state ~96 (32 AGPR acc + ~64 arch) -> fits (R14: no spill).
// LDS: 2x(16K+16K) = 64KB + aux ~2.6KB -> 2 blocks/CU (133KB <= 160KB).
// Separate instantiation per CACHED to keep regalloc clean per path.
template <int CACHED>
__global__ __launch_bounds__(BT, 4)
void mega_kernel(const float* feats, const int* labels, unsigned short* fb,
                 float* rp0, float* rp1, float* cp0, float* cp1,
                 float* tmn, float* tmx, floatx4* simsv, float* out) {
  __shared__ __align__(16) short As[2 * CHUNK_SH];
  __shared__ __align__(16) short Bs[2 * CHUNK_SH];
  __shared__ int   labA[BM];
  __shared__ float tA0[BM], tA1[BM];

  cg::grid_group grid = cg::this_grid();
  const int bid = blockIdx.x;
  const int tid = threadIdx.x;

  // phase 0: convert fp32 -> bf16 (+ init out)
  const int n4 = 8192 * D / 4;
  for (int i = bid * BT + tid; i < n4; i += NPB * BT) {
    float4 v = ((const float4*)feats)[i];
    unsigned lo = f2bf(v.x) | (f2bf(v.y) << 16);
    unsigned hi = f2bf(v.z) | (f2bf(v.w) << 16);
    ((uint2*)fb)[i] = make_uint2(lo, hi);
  }
  if (bid == 0 && tid == 0) { out[0] = 0.f; out[1] = 1.f; }
  __threadfence();
  grid.sync();

  // phase 1: pass1 (+ sim tile store when CACHED)
  pair_body<1, (bool)CACHED>(bid, fb, labels, nullptr, nullptr,
                             rp0, rp1, cp0, cp1, simsv,
                             As, Bs, labA, tA0, tA1);
  __threadfence();
  grid.sync();

  // phase 2: reduce1 -> thresholds
  if (bid < NT)
    reduce_body<1>(bid, rp0, rp1, cp0, cp1, tmn, tmx, out,
                   (float*)As, (float*)As + 384, (float*)As + 768);
  __threadfence();
  grid.sync();

  // phase 3: pass2 (cached: epilogue-only, streams sims back)
  pair_body<2, (bool)CACHED>(bid, fb, labels, tmn, tmx,
                             rp0, rp1, cp0, cp1, simsv,
                             As, Bs, labA, tA0, tA1);
  __threadfence();
  grid.sync();

  // phase 4: reduce2 + finalize (atomics onto out)
  if (bid < NT)
    reduce_body<2>(bid, rp0, rp1, cp0, cp1, nullptr, nullptr, out,
                   (float*)As, (float*)As + 384, (float*)As + 768);
}

// ---------------- fallback split kernels (compute-only) ---------------------
__global__ void convert_kernel(const float* __restrict__ feats,
                               unsigned short* __restrict__ fb, int n4,
                               float* __restrict__ out) {
  int i = blockIdx.x * blockDim.x + threadIdx.x;
  if (i < n4) {
    float4 v = ((const float4*)feats)[i];
    unsigned lo = f2bf(v.x) | (f2bf(v.y) << 16);
    unsigned hi = f2bf(v.z) | (f2bf(v.w) << 16);
    ((uint2*)fb)[i] = make_uint2(lo, hi);
  }
  if (blockIdx.x == 0 && threadIdx.x == 0) { out[0] = 0.f; out[1] = 1.f; }
}

template <int PASS>
__global__ __launch_bounds__(BT, 4)
void pair_kernel(const unsigned short* __restrict__ fb, const int* __restrict__ labels,
                 const float* __restrict__ tmn, const float* __restrict__ tmx,
                 float* __restrict__ rp0, float* __restrict__ rp1,
                 float* __restrict__ cp0, float* __restrict__ cp1) {
  __shared__ __align__(16) short As[2 * CHUNK_SH];
  __shared__ __align__(16) short Bs[2 * CHUNK_SH];
  __shared__ int   labA[BM];
  __shared__ float tA0[BM], tA1[BM];
  pair_body<PASS, false>(blockIdx.x, fb, labels, tmn, tmx, rp0, rp1, cp0, cp1,
                         nullptr, As, Bs, labA, tA0, tA1);
}

template <int PASS>
__global__ void reduce_kernel(const float* __restrict__ rp0, const float* __restrict__ rp1,
                              const float* __restrict__ cp0, const float* __restrict__ cp1,
                              float* __restrict__ o0, float* __restrict__ o1,
                              float* __restrict__ out) {
  __shared__ float sA[384], sB[384], sred[8];
  reduce_body<PASS>(blockIdx.x, rp0, rp1, cp0, cp1, o0, o1, out, sA, sB, sred);
}

extern "C" void kernel_launch(void* const* d_in, const int* in_sizes, int n_in,
                              void* d_out, int out_size, void* d_ws, size_t ws_size,
                              hipStream_t stream) {
  const float* feats  = (const float*)d_in[0];
  const int*   labels = (const int*)d_in[1];
  const int Bn = in_sizes[1];          // 8192
  float* out = (float*)d_out;

  char* base = (char*)d_ws;
  unsigned short* fb = (unsigned short*)base;                       // 4 MB
  size_t o = (size_t)Bn * D * 2;
  float* rp0 = (float*)(base + o);  o += (size_t)NPB * 256 * 4;
  float* rp1 = (float*)(base + o);  o += (size_t)NPB * 256 * 4;
  float* cp0 = (float*)(base + o);  o += (size_t)NT * CPS * 512 * 4;
  float* cp1 = (float*)(base + o);  o += (size_t)NT * CPS * 512 * 4;
  float* tmn = (float*)(base + o);  o += (size_t)Bn * 4;
  float* tmx = (float*)(base + o);  o += (size_t)Bn * 4;
  floatx4* simsv = (floatx4*)(base + o);
  size_t need = o + (size_t)TILE_SLOTS * TILE_V4 * 16;              // +138.4 MB
  const int cached = (ws_size >= need) ? 1 : 0;

  bool launched = false;
  int maxb = 0;
  const void* kfn = cached ? (const void*)mega_kernel<1> : (const void*)mega_kernel<0>;
  hipError_t qe = hipOccupancyMaxActiveBlocksPerMultiprocessor(&maxb, kfn, BT, 0);
  if (qe == hipSuccess && maxb * 256 >= NPB) {
    void* args[] = {(void*)&feats, (void*)&labels, (void*)&fb,
                    (void*)&rp0, (void*)&rp1, (void*)&cp0, (void*)&cp1,
                    (void*)&tmn, (void*)&tmx, (void*)&simsv, (void*)&out};
    hipError_t le = hipLaunchCooperativeKernel(kfn, dim3(NPB), dim3(BT), args, 0, stream);
    launched = (le == hipSuccess);
  }
  if (!launched) {
    int n4 = Bn * D / 4;
    convert_kernel<<<(n4 + 255) / 256, 256, 0, stream>>>(feats, fb, n4, out);
    pair_kernel<1><<<NPB, BT, 0, stream>>>(fb, labels, nullptr, nullptr, rp0, rp1, cp0, cp1);
    reduce_kernel<1><<<NT, BT, 0, stream>>>(rp0, rp1, cp0, cp1, tmn, tmx, out);
    pair_kernel<2><<<NPB, BT, 0, stream>>>(fb, labels, tmn, tmx, rp0, rp1, cp0, cp1);
    reduce_kernel<2><<<NT, BT, 0, stream>>>(rp0, rp1, cp0, cp1, nullptr, nullptr, out);
  }
}